// Round 2
// baseline (425.291 us; speedup 1.0000x reference)
//
#include <hip/hip_runtime.h>

#define HS   512
#define WSZ  512
#define NC   64
#define HW   (HS * WSZ)
#define KCAP  16   // legacy path: bin capacity (1 entry/ref-pixel)
#define KCAP9 32   // new path: 9-expanded bins, ~Poisson(9)/bin, max over 262k bins ~26

typedef unsigned int uint;
typedef unsigned short ushort;
typedef float f32x2 __attribute__((ext_vector_type(2)));

// float -> bf16 (round-to-nearest-even), raw bits
__device__ __forceinline__ ushort f2bf(float f) {
    uint b = __float_as_uint(f);
    return (ushort)((b + 0x7FFFu + ((b >> 16) & 1u)) >> 16);
}

// ---------------------------------------------------------------------------
// prep: transpose ref (C,H,W) f32 -> refu4 (H*W, 8) uint4 (packed bf16 pairs,
// 64 ch/pixel = 128B), zero bin counters.  float4 reads, uint4 writes.
// ---------------------------------------------------------------------------
__global__ __launch_bounds__(256) void prep_kernel(
    const float4* __restrict__ ref4, uint4* __restrict__ refu4,
    int* __restrict__ cnt)
{
    __shared__ float lds[64 * 65];
    const int p0  = blockIdx.x * 64;       // 64 pixels / tile
    const int tid = threadIdx.x;
    if (tid < 64) cnt[blockIdx.x * 64 + tid] = 0;    // 4096*64 == HW
#pragma unroll
    for (int k = 0; k < 4; ++k) {
        int e  = k * 256 + tid;            // 1024 float4 per tile
        int c  = e >> 4;                   // channel
        int i4 = e & 15;                   // pixel quad
        float4 v = ref4[(size_t)c * (HW / 4) + (p0 >> 2) + i4];
        lds[(i4 * 4 + 0) * 65 + c] = v.x;
        lds[(i4 * 4 + 1) * 65 + c] = v.y;
        lds[(i4 * 4 + 2) * 65 + c] = v.z;
        lds[(i4 * 4 + 3) * 65 + c] = v.w;
    }
    __syncthreads();
#pragma unroll
    for (int k = 0; k < 2; ++k) {
        int e = k * 256 + tid;             // 512 uint4 per tile
        int i = e >> 3;                    // pixel
        int q = e & 7;                     // channel octet
        const float* row = &lds[i * 65 + 8 * q];
        uint4 u;
        u.x = (uint)f2bf(row[0]) | ((uint)f2bf(row[1]) << 16);
        u.y = (uint)f2bf(row[2]) | ((uint)f2bf(row[3]) << 16);
        u.z = (uint)f2bf(row[4]) | ((uint)f2bf(row[5]) << 16);
        u.w = (uint)f2bf(row[6]) | ((uint)f2bf(row[7]) << 16);
        refu4[(size_t)(p0 + i) * 8 + q] = u;
    }
}

// ---------------------------------------------------------------------------
// Pre-expanded inverted map.  Each ref pixel r scatters into the NINE bins
// (targets) its nnf_rs vote touches; payload is the already-offset,
// already-validated source index q = r + d (18 bits).  This moves the entire
// tap-decode/SEL/prefix machinery out of the hot gather: gather pass-2
// becomes a flat walk of unconditionally-valid entries.
// ---------------------------------------------------------------------------
__global__ __launch_bounds__(256) void fill_bins9(
    const int2* __restrict__ nnf_rs, int* __restrict__ cnt,
    int* __restrict__ slots)
{
    int r  = blockIdx.x * 256 + threadIdx.x;
    int ry = r >> 9, rx = r & 511;
    int2 s = nnf_rs[r];                 // (sy, sx), values in [0,512)
#pragma unroll
    for (int dy = -1; dy <= 1; ++dy) {
#pragma unroll
        for (int dx = -1; dx <= 1; ++dx) {
            int ty = s.x + dy, tx = s.y + dx;   // target (bin) coord
            int qy = ry + dy,  qx = rx + dx;    // ref source coord
            bool v = ((unsigned)ty < 512u) & ((unsigned)tx < 512u) &
                     ((unsigned)qy < 512u) & ((unsigned)qx < 512u);
            if (v) {
                int bin = (ty << 9) | tx;
                int pos = atomicAdd(&cnt[bin], 1);
                if (pos < KCAP9) slots[(bin << 5) + pos] = (qy << 9) | qx;
            }
        }
    }
}

// ---------------------------------------------------------------------------
// gather9: 8 targets/wave, 8 lanes/target, lane covers 8 channels via one
// uint4.  Pass 2 is a flat entry walk (no SEL chain, no decode, no validity
// math — all resolved at fill time).  Accumulators are float2 ext-vectors to
// let LLVM form v_pk_fma_f32.
// ---------------------------------------------------------------------------
__global__ __launch_bounds__(256) void gather9(
    const uint4* __restrict__ refu4,
    const int2*  __restrict__ nnf_sr,
    const int*   __restrict__ cnt,
    const int*   __restrict__ slots,
    float* __restrict__ out)
{
    const float ws = 1.0f / 262144.0f;   // 2^-18 exact
    const float wr = 2.0f / 262144.0f;   // 2^-17 exact

    const int tid = threadIdx.x;
    const int k   = tid & 7;                       // channel octet
    const int t   = blockIdx.x * 32 + (tid >> 3);  // 32 targets / block
    const int ty  = t >> 9, tx = t & 511;

    const uint4* __restrict__ refk   = refu4 + k;       // lane-const offset
    const int*   __restrict__ slot_t = slots + (t << 5);
    const int S = min(cnt[t], KCAP9);                   // pass-2 entry count

    f32x2 A0 = {0.f, 0.f}, A1 = {0.f, 0.f}, A2 = {0.f, 0.f}, A3 = {0.f, 0.f};
    float w = 0.f;

#define ACCUM9(qv, mv)                                                        \
    {                                                                         \
        const int   q_ = (qv);                                                \
        const float m_ = (mv);                                                \
        const uint4 u_ = refk[(size_t)q_ * 8];                                \
        f32x2 m2_; m2_.x = m_; m2_.y = m_;                                    \
        f32x2 p_;                                                             \
        p_.x = __uint_as_float(u_.x << 16);                                   \
        p_.y = __uint_as_float(u_.x & 0xffff0000u);                           \
        A0 += p_ * m2_;                                                       \
        p_.x = __uint_as_float(u_.y << 16);                                   \
        p_.y = __uint_as_float(u_.y & 0xffff0000u);                           \
        A1 += p_ * m2_;                                                       \
        p_.x = __uint_as_float(u_.z << 16);                                   \
        p_.y = __uint_as_float(u_.z & 0xffff0000u);                           \
        A2 += p_ * m2_;                                                       \
        p_.x = __uint_as_float(u_.w << 16);                                   \
        p_.y = __uint_as_float(u_.w & 0xffff0000u);                           \
        A3 += p_ * m2_;                                                       \
        w += m_;                                                              \
    }

    // ---- pass 1 (src->ref gather), no bin bookkeeping ----
#define TAP9(dy, dx)                                                          \
    {                                                                         \
        const int sy = ty - (dy), sx = tx - (dx);                             \
        const bool sval = ((unsigned)sy < 512u) & ((unsigned)sx < 512u);      \
        const int sidx = ((sy & 511) << 9) | (sx & 511);                      \
        const int2 nn = nnf_sr[sidx];                                         \
        const int qy = nn.x + (dy), qx = nn.y + (dx);                         \
        const bool v = sval & ((unsigned)qy < 512u) & ((unsigned)qx < 512u);  \
        ACCUM9((((qy & 511) << 9) | (qx & 511)), v ? ws : 0.f)                \
    }

    TAP9(-1, -1)  TAP9(-1, 0)  TAP9(-1, 1)
    TAP9( 0, -1)  TAP9( 0, 0)  TAP9( 0, 1)
    TAP9( 1, -1)  TAP9( 1, 0)  TAP9( 1, 1)
#undef TAP9

    // ---- pass 2: flat walk of pre-validated entries (x2 unroll, int2) ----
    // Odd tail e.y is masked to a safe in-range index with weight 0 (refu4
    // holds only finite values, so x * 0 == 0); the int2 load itself stays
    // inside the 32-entry bin (max index 31).
    for (int s = 0; s < S; s += 2) {
        const int2 e = *(const int2*)(slot_t + s);
        ACCUM9(e.x & 0x3FFFF, wr)
        ACCUM9(e.y & 0x3FFFF, (s + 1 < S) ? wr : 0.f)
    }
#undef ACCUM9

    // ---- epilogue ----
    if (w == 0.f) w = 1.f;             // unreachable (center tap always valid)
    const float inv = 1.f / w;
    size_t o = (size_t)(8 * k) * HW + t;
    out[o]                = A0.x * inv;
    out[o + 1*(size_t)HW] = A0.y * inv;
    out[o + 2*(size_t)HW] = A1.x * inv;
    out[o + 3*(size_t)HW] = A1.y * inv;
    out[o + 4*(size_t)HW] = A2.x * inv;
    out[o + 5*(size_t)HW] = A2.y * inv;
    out[o + 6*(size_t)HW] = A3.x * inv;
    out[o + 7*(size_t)HW] = A3.y * inv;
}

// ===========================================================================
// LEGACY PATH (workspace < 65 MB): unchanged baseline pipeline.
// ===========================================================================
__global__ __launch_bounds__(256) void fill_bins(
    const int2* __restrict__ nnf_rs, int* __restrict__ cnt,
    int* __restrict__ slots)
{
    int r = blockIdx.x * 256 + threadIdx.x;
    int2 s = nnf_rs[r];                 // (sy, sx), values in [0,512)
    int bin = (s.x << 9) | s.y;
    int pos = atomicAdd(&cnt[bin], 1);
    if (pos < KCAP) slots[(bin << 4) + pos] = r;
}

template <bool PACKED>
__global__ __launch_bounds__(256) void gather8(
    const uint4* __restrict__ refu4,
    const float* __restrict__ reff,
    const int2*  __restrict__ nnf_sr,
    const int*   __restrict__ cnt,
    const int*   __restrict__ slots,
    float* __restrict__ out)
{
    const float ws = 1.0f / 262144.0f;   // 2^-18 exact
    const float wr = 2.0f / 262144.0f;   // 2^-17 exact

    const int tid = threadIdx.x;
    const int k   = tid & 7;                       // channel octet
    const int t   = blockIdx.x * 32 + (tid >> 3);  // 32 targets / block
    const int ty  = t >> 9, tx = t & 511;

    float a0=0,a1=0,a2=0,a3=0,a4=0,a5=0,a6=0,a7=0, w=0.f;

#define ACCUM(qv, mv)                                                         \
    {                                                                         \
        const int   q_ = (qv);                                                \
        const float m_ = (mv);                                                \
        if (PACKED) {                                                         \
            uint4 u_ = refu4[(size_t)q_ * 8 + k];                             \
            a0 += __uint_as_float(u_.x << 16)         * m_;                   \
            a1 += __uint_as_float(u_.x & 0xffff0000u) * m_;                   \
            a2 += __uint_as_float(u_.y << 16)         * m_;                   \
            a3 += __uint_as_float(u_.y & 0xffff0000u) * m_;                   \
            a4 += __uint_as_float(u_.z << 16)         * m_;                   \
            a5 += __uint_as_float(u_.z & 0xffff0000u) * m_;                   \
            a6 += __uint_as_float(u_.w << 16)         * m_;                   \
            a7 += __uint_as_float(u_.w & 0xffff0000u) * m_;                   \
        } else {                                                              \
            const size_t c0_ = (size_t)(8 * k) * HW + q_;                     \
            a0 += reff[c0_ + 0*(size_t)HW] * m_;                              \
            a1 += reff[c0_ + 1*(size_t)HW] * m_;                              \
            a2 += reff[c0_ + 2*(size_t)HW] * m_;                              \
            a3 += reff[c0_ + 3*(size_t)HW] * m_;                              \
            a4 += reff[c0_ + 4*(size_t)HW] * m_;                              \
            a5 += reff[c0_ + 5*(size_t)HW] * m_;                              \
            a6 += reff[c0_ + 6*(size_t)HW] * m_;                              \
            a7 += reff[c0_ + 7*(size_t)HW] * m_;                              \
        }                                                                     \
        w += m_;                                                              \
    }

    int mt0,mt1,mt2,mt3,mt4,mt5,mt6,mt7,mt8;
    int run = 0;

#define TAP(i, dy, dx)                                                        \
    {                                                                         \
        const int sy = ty - (dy), sx = tx - (dx);                             \
        const bool sval = ((unsigned)sy < 512u) & ((unsigned)sx < 512u);      \
        const int sidx = ((sy & 511) << 9) | (sx & 511);                      \
        mt##i = (sidx << 12) | ((i) << 8) | run;                              \
        const int c = cnt[sidx];                                              \
        run += sval ? min(c, KCAP) : 0;                                       \
        const int2 nn = nnf_sr[sidx];                                         \
        const int qy = nn.x + (dy), qx = nn.y + (dx);                         \
        const bool v = sval & ((unsigned)qy < 512u) & ((unsigned)qx < 512u);  \
        ACCUM((((qy & 511) << 9) | (qx & 511)), v ? ws : 0.f)                 \
    }

    TAP(0, -1, -1)  TAP(1, -1, 0)  TAP(2, -1, 1)
    TAP(3,  0, -1)  TAP(4,  0, 0)  TAP(5,  0, 1)
    TAP(6,  1, -1)  TAP(7,  1, 0)  TAP(8,  1, 1)
#undef TAP

    const int S = run;

#define SEL(i)  m_ = (s_ >= (mt##i & 255)) ? mt##i : m_;
#define ENTRY(sv)                                                             \
    {                                                                         \
        const int s_ = (sv);                                                  \
        int m_ = mt0;                                                         \
        SEL(1) SEL(2) SEL(3) SEL(4) SEL(5) SEL(6) SEL(7) SEL(8)               \
        const int off_ = m_ & 255;                                            \
        const int ii_  = (m_ >> 8) & 15;                                      \
        const int bs_  = (m_ >> 12) << 4;      /* slots base = sidx*16 */     \
        const int idx_ = min(s_ - off_, KCAP - 1);                            \
        const int e_   = slots[bs_ + idx_];                                   \
        const int ry_  = (e_ >> 9) & 511, rx_ = e_ & 511;                     \
        const int dyp_ = (ii_ * 11) >> 5;      /* ii/3 */                     \
        const int dy_  = dyp_ - 1, dx_ = ii_ - 3 * dyp_ - 1;                  \
        const int qy_  = ry_ + dy_, qx_ = rx_ + dx_;                          \
        const bool v_  = (s_ < S) &                                           \
                         ((unsigned)qy_ < 512u) & ((unsigned)qx_ < 512u);     \
        ACCUM((((qy_ & 511) << 9) | (qx_ & 511)), v_ ? wr : 0.f)              \
    }

    for (int s = 0; s < S; s += 2) {
        ENTRY(s)
        ENTRY(s + 1)
    }
#undef ENTRY
#undef SEL
#undef ACCUM

    if (w == 0.f) w = 1.f;
    const float inv = 1.f / w;
    size_t o = (size_t)(8 * k) * HW + t;
    out[o]                = a0 * inv;
    out[o + 1*(size_t)HW] = a1 * inv;
    out[o + 2*(size_t)HW] = a2 * inv;
    out[o + 3*(size_t)HW] = a3 * inv;
    out[o + 4*(size_t)HW] = a4 * inv;
    out[o + 5*(size_t)HW] = a5 * inv;
    out[o + 6*(size_t)HW] = a6 * inv;
    out[o + 7*(size_t)HW] = a7 * inv;
}

extern "C" void kernel_launch(void* const* d_in, const int* in_sizes, int n_in,
                              void* d_out, int out_size, void* d_ws, size_t ws_size,
                              hipStream_t stream)
{
    const float* ref    = (const float*)d_in[0];
    const int2*  nnf_sr = (const int2*)d_in[1];
    const int2*  nnf_rs = (const int2*)d_in[2];
    float* out = (float*)d_out;

    char* wsb = (char*)d_ws;
    const size_t refT_bytes  = (size_t)HW * NC * 2;        // 32 MiB packed bf16
    const size_t cnt_bytes   = (size_t)HW * 4;             //  1 MiB
    const size_t slot9_bytes = (size_t)HW * KCAP9 * 4;     // 32 MiB (new path)
    const size_t slot_bytes  = (size_t)HW * KCAP * 4;      // 16 MiB (legacy)

    if (ws_size >= refT_bytes + cnt_bytes + slot9_bytes) {
        // 9-expanded inverted bins — tap decode moved to fill time.
        uint4* refu4 = (uint4*)wsb;
        int*   cntp  = (int*)(wsb + refT_bytes);
        int*   slots = (int*)(wsb + refT_bytes + cnt_bytes);

        prep_kernel<<<HW / 64, 256, 0, stream>>>((const float4*)ref, refu4, cntp);
        fill_bins9<<<HW / 256, 256, 0, stream>>>(nnf_rs, cntp, slots);
        gather9<<<HW / 32, 256, 0, stream>>>(refu4, nnf_sr, cntp, slots, out);
    } else if (ws_size >= refT_bytes + cnt_bytes + slot_bytes) {
        // Legacy packed path (baseline).
        uint4* refu4 = (uint4*)wsb;
        int*   cntp  = (int*)(wsb + refT_bytes);
        int*   slots = (int*)(wsb + refT_bytes + cnt_bytes);

        prep_kernel<<<HW / 64, 256, 0, stream>>>((const float4*)ref, refu4, cntp);
        fill_bins<<<HW / 256, 256, 0, stream>>>(nnf_rs, cntp, slots);
        gather8<true><<<HW / 32, 256, 0, stream>>>(refu4, nullptr, nnf_sr,
                                                   cntp, slots, out);
    } else {
        // fallback: bins only, gather channel-major f32 ref directly
        int* cntp  = (int*)wsb;
        int* slots = cntp + HW;
        hipMemsetAsync(cntp, 0, cnt_bytes, stream);
        fill_bins<<<HW / 256, 256, 0, stream>>>(nnf_rs, cntp, slots);
        gather8<false><<<HW / 32, 256, 0, stream>>>(nullptr, ref, nnf_sr,
                                                    cntp, slots, out);
    }
}

// Round 3
// 227.413 us; speedup vs baseline: 1.8701x; 1.8701x over previous
//
#include <hip/hip_runtime.h>

#define HS   512
#define WSZ  512
#define NC   64
#define HW   (HS * WSZ)
#define KCAP 16     // inverted-map bin capacity (Poisson(1)/bin; P(>16) ~ 1e-14)
#define LCAP 32     // per-target LDS list capacity (Poisson(9); P(>32) ~ 3e-5 overall)

typedef unsigned int uint;
typedef unsigned short ushort;

// float -> bf16 (round-to-nearest-even), raw bits
__device__ __forceinline__ ushort f2bf(float f) {
    uint b = __float_as_uint(f);
    return (ushort)((b + 0x7FFFu + ((b >> 16) & 1u)) >> 16);
}

// ---------------------------------------------------------------------------
// prep: transpose ref (C,H,W) f32 -> refu4 (H*W, 8) uint4 (packed bf16 pairs,
// 64 ch/pixel = 128B), zero bin counters.  float4 reads, uint4 writes.
// ---------------------------------------------------------------------------
__global__ __launch_bounds__(256) void prep_kernel(
    const float4* __restrict__ ref4, uint4* __restrict__ refu4,
    int* __restrict__ cnt)
{
    __shared__ float lds[64 * 65];
    const int p0  = blockIdx.x * 64;       // 64 pixels / tile
    const int tid = threadIdx.x;
    if (tid < 64) cnt[blockIdx.x * 64 + tid] = 0;    // 4096*64 == HW
#pragma unroll
    for (int k = 0; k < 4; ++k) {
        int e  = k * 256 + tid;            // 1024 float4 per tile
        int c  = e >> 4;                   // channel
        int i4 = e & 15;                   // pixel quad
        float4 v = ref4[(size_t)c * (HW / 4) + (p0 >> 2) + i4];
        lds[(i4 * 4 + 0) * 65 + c] = v.x;
        lds[(i4 * 4 + 1) * 65 + c] = v.y;
        lds[(i4 * 4 + 2) * 65 + c] = v.z;
        lds[(i4 * 4 + 3) * 65 + c] = v.w;
    }
    __syncthreads();
#pragma unroll
    for (int k = 0; k < 2; ++k) {
        int e = k * 256 + tid;             // 512 uint4 per tile
        int i = e >> 3;                    // pixel
        int q = e & 7;                     // channel octet
        const float* row = &lds[i * 65 + 8 * q];
        uint4 u;
        u.x = (uint)f2bf(row[0]) | ((uint)f2bf(row[1]) << 16);
        u.y = (uint)f2bf(row[2]) | ((uint)f2bf(row[3]) << 16);
        u.z = (uint)f2bf(row[4]) | ((uint)f2bf(row[5]) << 16);
        u.w = (uint)f2bf(row[6]) | ((uint)f2bf(row[7]) << 16);
        refu4[(size_t)(p0 + i) * 8 + q] = u;
    }
}

// ---------------------------------------------------------------------------
// Inverted map: bin = nnf_rs scatter-target center, payload = ref pixel r.
// ONE atomic per pixel (the only scatter pattern that proved cheap).
// ---------------------------------------------------------------------------
__global__ __launch_bounds__(256) void fill_bins(
    const int2* __restrict__ nnf_rs, int* __restrict__ cnt,
    int* __restrict__ slots)
{
    int r = blockIdx.x * 256 + threadIdx.x;
    int2 s = nnf_rs[r];                 // (sy, sx), values in [0,512)
    int bin = (s.x << 9) | s.y;
    int pos = atomicAdd(&cnt[bin], 1);
    if (pos < KCAP) slots[(bin << 4) + pos] = r;
}

// ---------------------------------------------------------------------------
// gather_lds: 32 targets/block (one image row segment), 8 lanes/target over
// channel octets.  Phase E expands the 9-tap inverted contributions into
// per-target LDS lists (pre-offset, pre-validated q indices) — since all 32
// targets share one row, each neighbor-bin row contributes exactly ONE dy,
// so the pair space is 102 bins x 3 dx-taps.  Pass 2 is then a flat LDS-fed
// walk: no SEL chain, no tap decode, no validity math, slot chain in LDS.
// ---------------------------------------------------------------------------
__global__ __launch_bounds__(256) void gather_lds(
    const uint4* __restrict__ refu4,
    const int2*  __restrict__ nnf_sr,
    const int*   __restrict__ cnt,
    const int*   __restrict__ slots,
    float* __restrict__ out)
{
    const float ws = 1.0f / 262144.0f;   // 2^-18 exact
    const float wr = 2.0f / 262144.0f;   // 2^-17 exact

    __shared__ int lists[32][36];        // 36-int row: 16B-aligned, bank-spread
    __shared__ int lcnt[32];
    __shared__ int bcnt[102];            // 3 rows x 34 cols of neighbor bins

    const int tid = threadIdx.x;
    const int t0  = blockIdx.x * 32;     // 32 targets, all in row ty0
    const int ty0 = t0 >> 9, tx0 = t0 & 511;

    // ---- phase E0: stage neighbor-bin counts, zero list counters ----
    if (tid < 32) lcnt[tid] = 0;
    if (tid < 102) {
        const int jr = tid / 34, jc = tid - jr * 34;
        const int sy = ty0 + jr - 1, sx = tx0 + jc - 1;
        const bool sv = ((unsigned)sy < 512u) & ((unsigned)sx < 512u);
        bcnt[tid] = sv ? min(cnt[(sy << 9) | sx], KCAP) : 0;
    }
    __syncthreads();

    // ---- phase E1: expand 102 bins x 3 dx-taps into per-target lists ----
    for (int p = tid; p < 306; p += 256) {
        const int j  = p / 3;
        const int di = p - j * 3;              // dx = di-1
        const int jr = j / 34, jc = j - jr * 34;
        const int dy = 1 - jr;                 // unique dy for this bin row
        const int dx = di - 1;
        const int lt = jc - 1 + dx;            // local target index
        const int c  = bcnt[j];
        if (((unsigned)lt < 32u) && (c > 0)) {
            const int sy = ty0 + jr - 1, sx = tx0 + jc - 1;
            const int sbase = (((sy << 9) | sx) << 4);
            for (int e = 0; e < c; ++e) {
                const int r  = slots[sbase + e];
                const int qy = (r >> 9) + dy, qx = (r & 511) + dx;
                if (((unsigned)qy < 512u) & ((unsigned)qx < 512u)) {
                    const int pos = atomicAdd(&lcnt[lt], 1);
                    if (pos < LCAP) lists[lt][pos] = (qy << 9) | qx;
                }
            }
        }
    }
    __syncthreads();

    // ---- per-thread identity ----
    const int k  = tid & 7;                    // channel octet
    const int lt = tid >> 3;                   // local target
    const int t  = t0 + lt;
    const int ty = ty0, tx = t & 511;

    float a0=0,a1=0,a2=0,a3=0,a4=0,a5=0,a6=0,a7=0, w=0.f;

#define ACCUM(qv, mv)                                                         \
    {                                                                         \
        const int   q_ = (qv);                                                \
        const float m_ = (mv);                                                \
        uint4 u_ = refu4[(size_t)q_ * 8 + k];                                 \
        a0 += __uint_as_float(u_.x << 16)         * m_;                       \
        a1 += __uint_as_float(u_.x & 0xffff0000u) * m_;                       \
        a2 += __uint_as_float(u_.y << 16)         * m_;                       \
        a3 += __uint_as_float(u_.y & 0xffff0000u) * m_;                       \
        a4 += __uint_as_float(u_.z << 16)         * m_;                       \
        a5 += __uint_as_float(u_.z & 0xffff0000u) * m_;                       \
        a6 += __uint_as_float(u_.w << 16)         * m_;                       \
        a7 += __uint_as_float(u_.w & 0xffff0000u) * m_;                       \
        w += m_;                                                              \
    }

    // ---- pass 1 (src->ref gather), no bin bookkeeping ----
#define TAP(dy, dx)                                                           \
    {                                                                         \
        const int sy = ty - (dy), sx = tx - (dx);                             \
        const bool sval = ((unsigned)sy < 512u) & ((unsigned)sx < 512u);      \
        const int sidx = ((sy & 511) << 9) | (sx & 511);                      \
        const int2 nn = nnf_sr[sidx];                                         \
        const int qy = nn.x + (dy), qx = nn.y + (dx);                         \
        const bool v = sval & ((unsigned)qy < 512u) & ((unsigned)qx < 512u);  \
        ACCUM((((qy & 511) << 9) | (qx & 511)), v ? ws : 0.f)                 \
    }

    TAP(-1, -1)  TAP(-1, 0)  TAP(-1, 1)
    TAP( 0, -1)  TAP( 0, 0)  TAP( 0, 1)
    TAP( 1, -1)  TAP( 1, 0)  TAP( 1, 1)
#undef TAP

    // ---- pass 2: flat LDS-fed walk, x4 unroll (4 refu4 loads in flight) ----
    // Tail entries (s+i >= S) read stale LDS; index is masked into range and
    // weight forced to 0, so they contribute exactly nothing.
    const int S = min(lcnt[lt], LCAP);
    for (int s = 0; s < S; s += 4) {
        const int4 e4 = *(const int4*)&lists[lt][s];   // 16B-aligned ds_read
        ACCUM(e4.x & 0x3FFFF, wr)
        ACCUM(e4.y & 0x3FFFF, (s + 1 < S) ? wr : 0.f)
        ACCUM(e4.z & 0x3FFFF, (s + 2 < S) ? wr : 0.f)
        ACCUM(e4.w & 0x3FFFF, (s + 3 < S) ? wr : 0.f)
    }
#undef ACCUM

    // ---- epilogue ----
    if (w == 0.f) w = 1.f;             // unreachable (center tap always valid)
    const float inv = 1.f / w;
    size_t o = (size_t)(8 * k) * HW + t;
    out[o]                = a0 * inv;
    out[o + 1*(size_t)HW] = a1 * inv;
    out[o + 2*(size_t)HW] = a2 * inv;
    out[o + 3*(size_t)HW] = a3 * inv;
    out[o + 4*(size_t)HW] = a4 * inv;
    out[o + 5*(size_t)HW] = a5 * inv;
    out[o + 6*(size_t)HW] = a6 * inv;
    out[o + 7*(size_t)HW] = a7 * inv;
}

// ===========================================================================
// Fallback (tiny workspace): bins only, gather channel-major f32 ref with
// the SEL-chain walk.  Unchanged from baseline.
// ===========================================================================
__global__ __launch_bounds__(256) void gather8_f32(
    const float* __restrict__ reff,
    const int2*  __restrict__ nnf_sr,
    const int*   __restrict__ cnt,
    const int*   __restrict__ slots,
    float* __restrict__ out)
{
    const float ws = 1.0f / 262144.0f;
    const float wr = 2.0f / 262144.0f;

    const int tid = threadIdx.x;
    const int k   = tid & 7;
    const int t   = blockIdx.x * 32 + (tid >> 3);
    const int ty  = t >> 9, tx = t & 511;

    float a0=0,a1=0,a2=0,a3=0,a4=0,a5=0,a6=0,a7=0, w=0.f;

#define ACCUM(qv, mv)                                                         \
    {                                                                         \
        const int   q_ = (qv);                                                \
        const float m_ = (mv);                                                \
        const size_t c0_ = (size_t)(8 * k) * HW + q_;                         \
        a0 += reff[c0_ + 0*(size_t)HW] * m_;                                  \
        a1 += reff[c0_ + 1*(size_t)HW] * m_;                                  \
        a2 += reff[c0_ + 2*(size_t)HW] * m_;                                  \
        a3 += reff[c0_ + 3*(size_t)HW] * m_;                                  \
        a4 += reff[c0_ + 4*(size_t)HW] * m_;                                  \
        a5 += reff[c0_ + 5*(size_t)HW] * m_;                                  \
        a6 += reff[c0_ + 6*(size_t)HW] * m_;                                  \
        a7 += reff[c0_ + 7*(size_t)HW] * m_;                                  \
        w += m_;                                                              \
    }

    int mt0,mt1,mt2,mt3,mt4,mt5,mt6,mt7,mt8;
    int run = 0;

#define TAP(i, dy, dx)                                                        \
    {                                                                         \
        const int sy = ty - (dy), sx = tx - (dx);                             \
        const bool sval = ((unsigned)sy < 512u) & ((unsigned)sx < 512u);      \
        const int sidx = ((sy & 511) << 9) | (sx & 511);                      \
        mt##i = (sidx << 12) | ((i) << 8) | run;                              \
        const int c = cnt[sidx];                                              \
        run += sval ? min(c, KCAP) : 0;                                       \
        const int2 nn = nnf_sr[sidx];                                         \
        const int qy = nn.x + (dy), qx = nn.y + (dx);                         \
        const bool v = sval & ((unsigned)qy < 512u) & ((unsigned)qx < 512u);  \
        ACCUM((((qy & 511) << 9) | (qx & 511)), v ? ws : 0.f)                 \
    }

    TAP(0, -1, -1)  TAP(1, -1, 0)  TAP(2, -1, 1)
    TAP(3,  0, -1)  TAP(4,  0, 0)  TAP(5,  0, 1)
    TAP(6,  1, -1)  TAP(7,  1, 0)  TAP(8,  1, 1)
#undef TAP

    const int S = run;

#define SEL(i)  m_ = (s_ >= (mt##i & 255)) ? mt##i : m_;
#define ENTRY(sv)                                                             \
    {                                                                         \
        const int s_ = (sv);                                                  \
        int m_ = mt0;                                                         \
        SEL(1) SEL(2) SEL(3) SEL(4) SEL(5) SEL(6) SEL(7) SEL(8)               \
        const int off_ = m_ & 255;                                            \
        const int ii_  = (m_ >> 8) & 15;                                      \
        const int bs_  = (m_ >> 12) << 4;                                     \
        const int idx_ = min(s_ - off_, KCAP - 1);                            \
        const int e_   = slots[bs_ + idx_];                                   \
        const int ry_  = (e_ >> 9) & 511, rx_ = e_ & 511;                     \
        const int dyp_ = (ii_ * 11) >> 5;                                     \
        const int dy_  = dyp_ - 1, dx_ = ii_ - 3 * dyp_ - 1;                  \
        const int qy_  = ry_ + dy_, qx_ = rx_ + dx_;                          \
        const bool v_  = (s_ < S) &                                           \
                         ((unsigned)qy_ < 512u) & ((unsigned)qx_ < 512u);     \
        ACCUM((((qy_ & 511) << 9) | (qx_ & 511)), v_ ? wr : 0.f)              \
    }

    for (int s = 0; s < S; s += 2) {
        ENTRY(s)
        ENTRY(s + 1)
    }
#undef ENTRY
#undef SEL
#undef ACCUM

    if (w == 0.f) w = 1.f;
    const float inv = 1.f / w;
    size_t o = (size_t)(8 * k) * HW + t;
    out[o]                = a0 * inv;
    out[o + 1*(size_t)HW] = a1 * inv;
    out[o + 2*(size_t)HW] = a2 * inv;
    out[o + 3*(size_t)HW] = a3 * inv;
    out[o + 4*(size_t)HW] = a4 * inv;
    out[o + 5*(size_t)HW] = a5 * inv;
    out[o + 6*(size_t)HW] = a6 * inv;
    out[o + 7*(size_t)HW] = a7 * inv;
}

extern "C" void kernel_launch(void* const* d_in, const int* in_sizes, int n_in,
                              void* d_out, int out_size, void* d_ws, size_t ws_size,
                              hipStream_t stream)
{
    const float* ref    = (const float*)d_in[0];
    const int2*  nnf_sr = (const int2*)d_in[1];
    const int2*  nnf_rs = (const int2*)d_in[2];
    float* out = (float*)d_out;

    char* wsb = (char*)d_ws;
    const size_t refT_bytes = (size_t)HW * NC * 2;        // 32 MiB packed bf16
    const size_t cnt_bytes  = (size_t)HW * 4;             //  1 MiB
    const size_t slot_bytes = (size_t)HW * KCAP * 4;      // 16 MiB

    if (ws_size >= refT_bytes + cnt_bytes + slot_bytes) {   // 49 MiB
        uint4* refu4 = (uint4*)wsb;
        int*   cntp  = (int*)(wsb + refT_bytes);
        int*   slots = (int*)(wsb + refT_bytes + cnt_bytes);

        prep_kernel<<<HW / 64, 256, 0, stream>>>((const float4*)ref, refu4, cntp);
        fill_bins<<<HW / 256, 256, 0, stream>>>(nnf_rs, cntp, slots);
        gather_lds<<<HW / 32, 256, 0, stream>>>(refu4, nnf_sr, cntp, slots, out);
    } else {
        // fallback: bins only, gather channel-major f32 ref directly
        int* cntp  = (int*)wsb;
        int* slots = cntp + HW;
        hipMemsetAsync(cntp, 0, cnt_bytes, stream);
        fill_bins<<<HW / 256, 256, 0, stream>>>(nnf_rs, cntp, slots);
        gather8_f32<<<HW / 32, 256, 0, stream>>>(ref, nnf_sr, cntp, slots, out);
    }
}

// Round 4
// 217.548 us; speedup vs baseline: 1.9549x; 1.0453x over previous
//
#include <hip/hip_runtime.h>

#define HS   512
#define WSZ  512
#define NC   64
#define HW   (HS * WSZ)
#define KCAP 16       // inverted-map bin capacity (Poisson(1)/bin; P(>16) ~ 1e-14)
#define LCAP 32       // per-target LDS list capacity (Poisson(9); P(>32) ~ 3e-5 overall)
#define SENT 0x40000  // sentinel q -> zeroed pixel record appended at refu4[HW]

typedef unsigned int uint;
typedef unsigned short ushort;

// float -> bf16 (round-to-nearest-even), raw bits
__device__ __forceinline__ ushort f2bf(float f) {
    uint b = __float_as_uint(f);
    return (ushort)((b + 0x7FFFu + ((b >> 16) & 1u)) >> 16);
}

// ---------------------------------------------------------------------------
// FUSED prep + fill.  Blocks [0,4096): transpose ref (C,H,W) f32 ->
// refu4 (H*W+1, 8) uint4 (packed bf16 pairs, 128B/pixel).  Blocks
// [4096,5120): invert nnf_rs into bins (1 atomic/pixel — the only scatter
// pattern that proved cheap; round-2's 9-way scatter was 226 us).  Block
// 4096 additionally zeroes the sentinel record refu4[HW].  cnt is zeroed by
// a hipMemsetAsync issued before this kernel, so fill blocks may run
// concurrently with prep blocks (disjoint outputs, latency-bound fill
// overlaps BW-bound transpose).
// ---------------------------------------------------------------------------
__global__ __launch_bounds__(256) void prep_fill(
    const float4* __restrict__ ref4, uint4* __restrict__ refu4,
    const int2* __restrict__ nnf_rs, int* __restrict__ cnt,
    int* __restrict__ slots)
{
    __shared__ float lds[64 * 65];
    const int tid = threadIdx.x;

    if (blockIdx.x < 4096) {
        const int p0 = blockIdx.x * 64;        // 64 pixels / tile
#pragma unroll
        for (int k = 0; k < 4; ++k) {
            int e  = k * 256 + tid;            // 1024 float4 per tile
            int c  = e >> 4;                   // channel
            int i4 = e & 15;                   // pixel quad
            float4 v = ref4[(size_t)c * (HW / 4) + (p0 >> 2) + i4];
            lds[(i4 * 4 + 0) * 65 + c] = v.x;
            lds[(i4 * 4 + 1) * 65 + c] = v.y;
            lds[(i4 * 4 + 2) * 65 + c] = v.z;
            lds[(i4 * 4 + 3) * 65 + c] = v.w;
        }
        __syncthreads();
#pragma unroll
        for (int k = 0; k < 2; ++k) {
            int e = k * 256 + tid;             // 512 uint4 per tile
            int i = e >> 3;                    // pixel
            int q = e & 7;                     // channel octet
            const float* row = &lds[i * 65 + 8 * q];
            uint4 u;
            u.x = (uint)f2bf(row[0]) | ((uint)f2bf(row[1]) << 16);
            u.y = (uint)f2bf(row[2]) | ((uint)f2bf(row[3]) << 16);
            u.z = (uint)f2bf(row[4]) | ((uint)f2bf(row[5]) << 16);
            u.w = (uint)f2bf(row[6]) | ((uint)f2bf(row[7]) << 16);
            refu4[(size_t)(p0 + i) * 8 + q] = u;
        }
    } else {
        if (blockIdx.x == 4096 && tid < 8) {   // zero the sentinel record
            uint4 z; z.x = 0u; z.y = 0u; z.z = 0u; z.w = 0u;
            refu4[(size_t)HW * 8 + tid] = z;
        }
        const int r = (blockIdx.x - 4096) * 256 + tid;
        const int2 s = nnf_rs[r];              // (sy, sx), values in [0,512)
        const int bin = (s.x << 9) | s.y;
        const int pos = atomicAdd(&cnt[bin], 1);
        if (pos < KCAP) slots[(bin << 4) + pos] = r;
    }
}

// ---------------------------------------------------------------------------
// gather_lds: 32 targets/block (one image row segment), 8 lanes/target over
// channel octets.  Phase E expands the 9-tap inverted contributions into
// per-target LDS lists (pre-offset, pre-validated q indices).  New vs R3:
//   * nnf_sr for the 102 neighbor bins staged in LDS (kills 9 redundant
//     8x-lane-duplicated global loads per thread in pass 1),
//   * all per-entry weight math factored out: ws = wr/2 exactly, so
//     out = wr*(0.5*sum_pass1 + sum_pass2)/w with w = ws*nv + wr*S
//     (nv = valid pass-1 taps, S = real pass-2 entries) — ACCUM is pure
//     unpack+add, no per-entry cndmask / w accumulation,
//   * lists pre-filled with SENT (zeroed pixel record) -> maskless,
//     4-aligned pass-2 walk with no tail selects.
// ---------------------------------------------------------------------------
__global__ __launch_bounds__(256) void gather_lds(
    const uint4* __restrict__ refu4,
    const int2*  __restrict__ nnf_sr,
    const int*   __restrict__ cnt,
    const int*   __restrict__ slots,
    float* __restrict__ out)
{
    const float ws = 1.0f / 262144.0f;   // 2^-18 exact
    const float wr = 2.0f / 262144.0f;   // 2^-17 exact

    __shared__ __align__(16) int lists[32][36];  // 36-int rows: 16B-aligned
    __shared__ int  lcnt[32];
    __shared__ int  bcnt[102];           // 3 rows x 34 cols of neighbor bins
    __shared__ int2 snn[102];            // nnf_sr staged for the same bins

    const int tid = threadIdx.x;
    const int t0  = blockIdx.x * 32;     // 32 targets, all in row ty0
    const int ty0 = t0 >> 9, tx0 = t0 & 511;

    // ---- phase E0: stage bin counts + nnf_sr, SENT-fill lists ----
    if (tid < 32) lcnt[tid] = 0;
    if (tid < 102) {
        const int jr = tid / 34, jc = tid - jr * 34;
        const int sy = ty0 + jr - 1, sx = tx0 + jc - 1;
        const bool sv = ((unsigned)sy < 512u) & ((unsigned)sx < 512u);
        const int sidx = ((sy & 511) << 9) | (sx & 511);   // clamped-in-range
        bcnt[tid] = sv ? min(cnt[sidx], KCAP) : 0;
        snn[tid]  = nnf_sr[sidx];        // garbage ok when !sv (masked later)
    }
    {
        int4 s4; s4.x = SENT; s4.y = SENT; s4.z = SENT; s4.w = SENT;
        for (int p = tid; p < 288; p += 256)       // 32*36 ints = 288 int4
            ((int4*)lists)[p] = s4;
    }
    __syncthreads();

    // ---- phase E1: expand 102 bins x 3 dx-taps into per-target lists ----
    // (identical to R3 — proven)
    for (int p = tid; p < 306; p += 256) {
        const int j  = p / 3;
        const int di = p - j * 3;              // dx = di-1
        const int jr = j / 34, jc = j - jr * 34;
        const int dy = 1 - jr;                 // unique dy for this bin row
        const int dx = di - 1;
        const int lt = jc - 1 + dx;            // local target index
        const int c  = bcnt[j];
        if (((unsigned)lt < 32u) && (c > 0)) {
            const int sy = ty0 + jr - 1, sx = tx0 + jc - 1;
            const int sbase = (((sy << 9) | sx) << 4);
            for (int e = 0; e < c; ++e) {
                const int r  = slots[sbase + e];
                const int qy = (r >> 9) + dy, qx = (r & 511) + dx;
                if (((unsigned)qy < 512u) & ((unsigned)qx < 512u)) {
                    const int pos = atomicAdd(&lcnt[lt], 1);
                    if (pos < LCAP) lists[lt][pos] = (qy << 9) | qx;
                }
            }
        }
    }
    __syncthreads();

    // ---- per-thread identity ----
    const int k  = tid & 7;                    // channel octet
    const int lt = tid >> 3;                   // local target

    float a0=0,a1=0,a2=0,a3=0,a4=0,a5=0,a6=0,a7=0;
    int nv = 0;

#define ACCUM(qv)                                                             \
    {                                                                         \
        const uint4 u_ = refu4[(size_t)(qv) * 8 + k];                         \
        a0 += __uint_as_float(u_.x << 16);                                    \
        a1 += __uint_as_float(u_.x & 0xffff0000u);                            \
        a2 += __uint_as_float(u_.y << 16);                                    \
        a3 += __uint_as_float(u_.y & 0xffff0000u);                            \
        a4 += __uint_as_float(u_.z << 16);                                    \
        a5 += __uint_as_float(u_.z & 0xffff0000u);                            \
        a6 += __uint_as_float(u_.w << 16);                                    \
        a7 += __uint_as_float(u_.w & 0xffff0000u);                            \
    }

    // ---- pass 1 (src->ref gather): snn-fed, sentinel-masked plain adds ----
#define TAP(dy, dx)                                                           \
    {                                                                         \
        const bool rv = ((unsigned)(ty0 - (dy)) < 512u);      /* uniform */   \
        const bool cv = ((unsigned)(tx0 + lt - (dx)) < 512u);                 \
        const int2 nn = snn[(1 - (dy)) * 34 + (lt - (dx) + 1)];               \
        const int qy = nn.x + (dy), qx = nn.y + (dx);                         \
        const bool v = rv & cv &                                              \
                       ((unsigned)qy < 512u) & ((unsigned)qx < 512u);         \
        const int q = v ? ((qy << 9) | qx) : SENT;                            \
        nv += v ? 1 : 0;                                                      \
        ACCUM(q)                                                              \
    }

    TAP(-1, -1)  TAP(-1, 0)  TAP(-1, 1)
    TAP( 0, -1)  TAP( 0, 0)  TAP( 0, 1)
    TAP( 1, -1)  TAP( 1, 0)  TAP( 1, 1)
#undef TAP

    // fold pass-1 into pass-2 scale domain: ws = 0.5*wr (exact pow2 scale)
    a0 *= 0.5f; a1 *= 0.5f; a2 *= 0.5f; a3 *= 0.5f;
    a4 *= 0.5f; a5 *= 0.5f; a6 *= 0.5f; a7 *= 0.5f;

    // ---- pass 2: maskless 4-aligned walk (tail entries are SENT = zeros) --
    const int Sreal = min(lcnt[lt], LCAP);
    const int S4 = (Sreal + 3) & ~3;
    for (int s = 0; s < S4; s += 4) {
        const int4 e4 = *(const int4*)&lists[lt][s];   // 16B-aligned ds_read
        ACCUM(e4.x)
        ACCUM(e4.y)
        ACCUM(e4.z)
        ACCUM(e4.w)
    }
#undef ACCUM

    // ---- epilogue: w = ws*nv + wr*Sreal (exact); out = a * wr / w ----
    const float wsum = ws * (float)nv + wr * (float)Sreal;   // nv>=1 always
    const float sc = wr / wsum;
    const int t = t0 + lt;
    size_t o = (size_t)(8 * k) * HW + t;
    out[o]                = a0 * sc;
    out[o + 1*(size_t)HW] = a1 * sc;
    out[o + 2*(size_t)HW] = a2 * sc;
    out[o + 3*(size_t)HW] = a3 * sc;
    out[o + 4*(size_t)HW] = a4 * sc;
    out[o + 5*(size_t)HW] = a5 * sc;
    out[o + 6*(size_t)HW] = a6 * sc;
    out[o + 7*(size_t)HW] = a7 * sc;
}

// ===========================================================================
// Fallback (tiny workspace): bins only, gather channel-major f32 ref with
// the SEL-chain walk.  Unchanged from baseline.
// ===========================================================================
__global__ __launch_bounds__(256) void fill_bins(
    const int2* __restrict__ nnf_rs, int* __restrict__ cnt,
    int* __restrict__ slots)
{
    int r = blockIdx.x * 256 + threadIdx.x;
    int2 s = nnf_rs[r];
    int bin = (s.x << 9) | s.y;
    int pos = atomicAdd(&cnt[bin], 1);
    if (pos < KCAP) slots[(bin << 4) + pos] = r;
}

__global__ __launch_bounds__(256) void gather8_f32(
    const float* __restrict__ reff,
    const int2*  __restrict__ nnf_sr,
    const int*   __restrict__ cnt,
    const int*   __restrict__ slots,
    float* __restrict__ out)
{
    const float ws = 1.0f / 262144.0f;
    const float wr = 2.0f / 262144.0f;

    const int tid = threadIdx.x;
    const int k   = tid & 7;
    const int t   = blockIdx.x * 32 + (tid >> 3);
    const int ty  = t >> 9, tx = t & 511;

    float a0=0,a1=0,a2=0,a3=0,a4=0,a5=0,a6=0,a7=0, w=0.f;

#define ACCUM(qv, mv)                                                         \
    {                                                                         \
        const int   q_ = (qv);                                                \
        const float m_ = (mv);                                                \
        const size_t c0_ = (size_t)(8 * k) * HW + q_;                         \
        a0 += reff[c0_ + 0*(size_t)HW] * m_;                                  \
        a1 += reff[c0_ + 1*(size_t)HW] * m_;                                  \
        a2 += reff[c0_ + 2*(size_t)HW] * m_;                                  \
        a3 += reff[c0_ + 3*(size_t)HW] * m_;                                  \
        a4 += reff[c0_ + 4*(size_t)HW] * m_;                                  \
        a5 += reff[c0_ + 5*(size_t)HW] * m_;                                  \
        a6 += reff[c0_ + 6*(size_t)HW] * m_;                                  \
        a7 += reff[c0_ + 7*(size_t)HW] * m_;                                  \
        w += m_;                                                              \
    }

    int mt0,mt1,mt2,mt3,mt4,mt5,mt6,mt7,mt8;
    int run = 0;

#define TAP(i, dy, dx)                                                        \
    {                                                                         \
        const int sy = ty - (dy), sx = tx - (dx);                             \
        const bool sval = ((unsigned)sy < 512u) & ((unsigned)sx < 512u);      \
        const int sidx = ((sy & 511) << 9) | (sx & 511);                      \
        mt##i = (sidx << 12) | ((i) << 8) | run;                              \
        const int c = cnt[sidx];                                              \
        run += sval ? min(c, KCAP) : 0;                                      \
        const int2 nn = nnf_sr[sidx];                                         \
        const int qy = nn.x + (dy), qx = nn.y + (dx);                         \
        const bool v = sval & ((unsigned)qy < 512u) & ((unsigned)qx < 512u);  \
        ACCUM((((qy & 511) << 9) | (qx & 511)), v ? ws : 0.f)                 \
    }

    TAP(0, -1, -1)  TAP(1, -1, 0)  TAP(2, -1, 1)
    TAP(3,  0, -1)  TAP(4,  0, 0)  TAP(5,  0, 1)
    TAP(6,  1, -1)  TAP(7,  1, 0)  TAP(8,  1, 1)
#undef TAP

    const int S = run;

#define SEL(i)  m_ = (s_ >= (mt##i & 255)) ? mt##i : m_;
#define ENTRY(sv)                                                             \
    {                                                                         \
        const int s_ = (sv);                                                  \
        int m_ = mt0;                                                         \
        SEL(1) SEL(2) SEL(3) SEL(4) SEL(5) SEL(6) SEL(7) SEL(8)               \
        const int off_ = m_ & 255;                                            \
        const int ii_  = (m_ >> 8) & 15;                                      \
        const int bs_  = (m_ >> 12) << 4;                                     \
        const int idx_ = min(s_ - off_, KCAP - 1);                            \
        const int e_   = slots[bs_ + idx_];                                   \
        const int ry_  = (e_ >> 9) & 511, rx_ = e_ & 511;                     \
        const int dyp_ = (ii_ * 11) >> 5;                                     \
        const int dy_  = dyp_ - 1, dx_ = ii_ - 3 * dyp_ - 1;                  \
        const int qy_  = ry_ + dy_, qx_ = rx_ + dx_;                          \
        const bool v_  = (s_ < S) &                                           \
                         ((unsigned)qy_ < 512u) & ((unsigned)qx_ < 512u);     \
        ACCUM((((qy_ & 511) << 9) | (qx_ & 511)), v_ ? wr : 0.f)              \
    }

    for (int s = 0; s < S; s += 2) {
        ENTRY(s)
        ENTRY(s + 1)
    }
#undef ENTRY
#undef SEL
#undef ACCUM

    if (w == 0.f) w = 1.f;
    const float inv = 1.f / w;
    size_t o = (size_t)(8 * k) * HW + t;
    out[o]                = a0 * inv;
    out[o + 1*(size_t)HW] = a1 * inv;
    out[o + 2*(size_t)HW] = a2 * inv;
    out[o + 3*(size_t)HW] = a3 * inv;
    out[o + 4*(size_t)HW] = a4 * inv;
    out[o + 5*(size_t)HW] = a5 * inv;
    out[o + 6*(size_t)HW] = a6 * inv;
    out[o + 7*(size_t)HW] = a7 * inv;
}

extern "C" void kernel_launch(void* const* d_in, const int* in_sizes, int n_in,
                              void* d_out, int out_size, void* d_ws, size_t ws_size,
                              hipStream_t stream)
{
    const float* ref    = (const float*)d_in[0];
    const int2*  nnf_sr = (const int2*)d_in[1];
    const int2*  nnf_rs = (const int2*)d_in[2];
    float* out = (float*)d_out;

    char* wsb = (char*)d_ws;
    const size_t refT_bytes = (size_t)HW * NC * 2 + 128;  // +128B sentinel rec
    const size_t cnt_bytes  = (size_t)HW * 4;             //  1 MiB
    const size_t slot_bytes = (size_t)HW * KCAP * 4;      // 16 MiB

    if (ws_size >= refT_bytes + cnt_bytes + slot_bytes) {   // ~49 MiB
        uint4* refu4 = (uint4*)wsb;
        int*   cntp  = (int*)(wsb + refT_bytes);
        int*   slots = (int*)(wsb + refT_bytes + cnt_bytes);

        hipMemsetAsync(cntp, 0, cnt_bytes, stream);
        prep_fill<<<4096 + HW / 256, 256, 0, stream>>>(
            (const float4*)ref, refu4, nnf_rs, cntp, slots);
        gather_lds<<<HW / 32, 256, 0, stream>>>(refu4, nnf_sr, cntp, slots, out);
    } else {
        // fallback: bins only, gather channel-major f32 ref directly
        int* cntp  = (int*)wsb;
        int* slots = cntp + HW;
        hipMemsetAsync(cntp, 0, cnt_bytes, stream);
        fill_bins<<<HW / 256, 256, 0, stream>>>(nnf_rs, cntp, slots);
        gather8_f32<<<HW / 32, 256, 0, stream>>>(ref, nnf_sr, cntp, slots, out);
    }
}